// Round 1
// baseline (340.626 us; speedup 1.0000x reference)
//
#include <hip/hip_runtime.h>
#include <hip/hip_fp16.h>
#include <math.h>

#define N_NODES 50000
#define N_EDGES 600000
#define TOT (N_EDGES + N_NODES)   // 650000 edges incl. self-loops
#define HD 128
#define OUTW 384
#define NEG_SLOPE 0.2f

// ---------- helpers ----------

typedef _Float16 h2_t __attribute__((ext_vector_type(2)));

static __device__ __forceinline__ float fdot2f(h2_t a, h2_t b, float c){
#if __has_builtin(__builtin_amdgcn_fdot2)
  return __builtin_amdgcn_fdot2(a, b, c, false);
#else
  return fmaf((float)a[0], (float)b[0], fmaf((float)a[1], (float)b[1], c));
#endif
}

// edge_index may arrive as int32 or int64; runtime-detected flag (uniform branch)
static __device__ __forceinline__ int load_edge(const void* ei, int is64, long long off){
  return is64 ? (int)((const long long*)ei)[off] : ((const int*)ei)[off];
}

// ---------- one-time per-launch kernels ----------

// fused: int64-layout detect + ce0/ce1 = dot(We, att_e) + scal[0] zero-init
__global__ __launch_bounds__(128) void prep_kernel(const void* ei, int* flag,
                                                   const float* __restrict__ We0, const float* __restrict__ ae0,
                                                   const float* __restrict__ We1, const float* __restrict__ ae1,
                                                   float* scal){
  __shared__ float buf[128];
  __shared__ int okbuf;
  int t = threadIdx.x;
  if (t == 0) okbuf = 1;
  __syncthreads();
  if (t < 64){
    long long v = ((const long long*)ei)[t];
    if (v < 0 || v >= N_NODES) atomicAnd(&okbuf, 0);
  }
  buf[t] = We0[t] * ae0[t];
  __syncthreads();
  for (int off = 64; off > 0; off >>= 1){ if (t < off) buf[t] += buf[t + off]; __syncthreads(); }
  if (t == 0) scal[1] = buf[0];
  __syncthreads();
  buf[t] = We1[t] * ae1[t];
  __syncthreads();
  for (int off = 64; off > 0; off >>= 1){ if (t < off) buf[t] += buf[t + off]; __syncthreads(); }
  if (t == 0){ scal[2] = buf[0]; scal[0] = 0.f; *flag = okbuf; }
}

// convert both weight matrices to k-paired fp16 layout: Wt[k2*128 + n] = (W[n][2k2], W[n][2k2+1])
__global__ __launch_bounds__(256) void wconv_kernel(const float* __restrict__ W0, const float* __restrict__ W1,
                                                    __half2* __restrict__ Wt0, __half2* __restrict__ Wt1){
  int e = blockIdx.x * 256 + threadIdx.x;     // 0..16383
  if (e >= 16384) return;
  const float* W = (e < 8192) ? W0 : W1;
  __half2* Wt = (e < 8192) ? Wt0 : Wt1;
  int i = e & 8191;
  int n = i & 127, k2 = i >> 7;
  float a = W[n * HD + 2 * k2];
  float b = W[n * HD + 2 * k2 + 1];
  Wt[k2 * 128 + n] = __floats2half2_rn(a, b);
}

// x -> fp16 copy (gemm0 input) + stream x into out[:,0:128] (JK-cat slot 0)
__global__ __launch_bounds__(256) void xconv_kernel(const float* __restrict__ x,
                                                    __half* __restrict__ x16,
                                                    float* __restrict__ out){
  int idx = blockIdx.x * 256 + threadIdx.x;   // one float4 per thread
  if (idx >= N_NODES * HD / 4) return;
  int n = idx >> 5, c4 = idx & 31;
  float4 v = ((const float4*)x)[idx];
  *(float4*)&out[(size_t)n * OUTW + c4 * 4] = v;
  float2 pk;
  ((__half2*)&pk)[0] = __floats2half2_rn(v.x, v.y);
  ((__half2*)&pk)[1] = __floats2half2_rn(v.z, v.w);
  *(float2*)&x16[(size_t)idx * 4] = pk;
}

__global__ __launch_bounds__(256) void mean_kernel(const float* __restrict__ ea, float* meansum){
  int tid = blockIdx.x * blockDim.x + threadIdx.x;
  float s = 0.f;
  for (int i = tid; i < N_EDGES; i += gridDim.x * blockDim.x) s += ea[i];
  for (int off = 32; off > 0; off >>= 1) s += __shfl_down(s, off, 64);
  __shared__ float ws[4];
  int lane = threadIdx.x & 63, w = threadIdx.x >> 6;
  if (lane == 0) ws[w] = s;
  __syncthreads();
  if (threadIdx.x == 0){
    atomicAdd(meansum, ws[0] + ws[1] + ws[2] + ws[3]);
  }
}

// degree count + one-time int64 -> int32 src/dst decode (coalesced write)
__global__ __launch_bounds__(256) void degconv_kernel(const void* ei, const int* flag, int* deg,
                                                      int* __restrict__ src32, int* __restrict__ dst32){
  int e = blockIdx.x * 256 + threadIdx.x;
  if (e >= TOT) return;
  int is64 = *flag;
  int d;
  if (e < N_EDGES){
    int s = load_edge(ei, is64, e);
    d = load_edge(ei, is64, (long long)N_EDGES + e);
    src32[e] = s;
    dst32[e] = d;
  } else {
    d = e - N_EDGES;
  }
  atomicAdd(&deg[d], 1);
}

// exclusive scan of deg[0..N) -> rowstart, 1024-element chunks
__global__ __launch_bounds__(256) void scan_chunk_kernel(const int* __restrict__ deg,
                                                         int* __restrict__ rowstart,
                                                         int* __restrict__ chunksums){
  __shared__ int sums[256];
  int t = threadIdx.x;
  int base = blockIdx.x * 1024 + t * 4;
  int v[4];
  #pragma unroll
  for (int i = 0; i < 4; i++) v[i] = (base + i < N_NODES) ? deg[base + i] : 0;
  int tsum = v[0] + v[1] + v[2] + v[3];
  sums[t] = tsum;
  __syncthreads();
  for (int off = 1; off < 256; off <<= 1){
    int add = (t >= off) ? sums[t - off] : 0;
    __syncthreads();
    sums[t] += add;
    __syncthreads();
  }
  int run = sums[t] - tsum;
  #pragma unroll
  for (int i = 0; i < 4; i++){
    if (base + i < N_NODES) rowstart[base + i] = run;
    run += v[i];
  }
  if (t == 255) chunksums[blockIdx.x] = sums[255];
}

__global__ void scan_top_kernel(int* chunksums, int nchunks){
  if (threadIdx.x == 0 && blockIdx.x == 0){
    int run = 0;
    for (int c = 0; c < nchunks; c++){ int v = chunksums[c]; chunksums[c] = run; run += v; }
  }
}

// add chunk offsets; also emit a second copy (rowcur) used as the fill cursor
__global__ __launch_bounds__(256) void add_off_kernel(int* rowstart, int* rowcur, const int* chunksums){
  int base = blockIdx.x * 1024 + threadIdx.x * 4;
  int off = chunksums[blockIdx.x];
  #pragma unroll
  for (int i = 0; i < 4; i++){
    if (base + i < N_NODES){
      int v = rowstart[base + i] + off;
      rowstart[base + i] = v;
      rowcur[base + i] = v;
    }
  }
}

// bucket fill: one packed int2 (src, eid) scattered store per edge
__global__ __launch_bounds__(256) void fill_kernel(const int* __restrict__ src32,
                                                   const int* __restrict__ dst32,
                                                   int* rowcur, int2* __restrict__ csr){
  int e = blockIdx.x * 256 + threadIdx.x;
  if (e >= TOT) return;
  int s, d;
  if (e < N_EDGES){
    s = src32[e];
    d = dst32[e];
  } else {
    s = d = e - N_EDGES;
  }
  int pos = atomicAdd(&rowcur[d], 1);
  csr[pos] = make_int2(s, e);
}

// ---------- per-layer kernels ----------

// fdot2 GEMM: hp_h[M,128] = fp16( hin[M,128] @ W^T ), fp16 input, W pre-packed fp16 [k2][n].
// BM=128 rows/block, 256 threads (4 waves), 8 rows x 8 cols per thread.
// LDS exactly 64 KB: A [k2][m] 32 KB + W [k2][n] 32 KB; ONE barrier; 2 blocks/CU (8 waves).
// Fused epilogue: ssrc/sdst row dots.
#define BM 128

__global__ __launch_bounds__(256, 2) void gemm_kernel(const __half* __restrict__ hin,
                                                      const __half2* __restrict__ Wt,
                                                      __half* __restrict__ hp_h,
                                                      const float* __restrict__ as_,
                                                      const float* __restrict__ ad_,
                                                      float* __restrict__ ssrc,
                                                      float* __restrict__ sdst){
  __shared__ __half2 As2[64 * 128];    // [k2][m] 32768 B
  __shared__ __half2 Wh2[64 * 128];    // [k2][n] 32768 B
  int t  = threadIdx.x;
  int tx = t & 15;
  int ty = t >> 4;                     // 0..15 -> rows ty*8..+7
  int rb = blockIdx.x * BM;

  // stage W: straight 32KB copy (coalesced, conflict-free)
  {
    const float4* src = (const float4*)Wt;
    float4* dst = (float4*)Wh2;
    #pragma unroll
    for (int p = 0; p < 8; p++) dst[t + p * 256] = src[t + p * 256];
  }
  // stage A: 128 rows x 128 halves, packed to [k2][m]
  #pragma unroll
  for (int p = 0; p < 8; p++){
    int idx = t + p * 256;             // 0..2047 float4s (8 halves each)
    int row = idx >> 4, c8 = idx & 15;
    int gr = rb + row; if (gr >= N_NODES) gr = N_NODES - 1;
    float4 v = *(const float4*)&hin[(size_t)gr * HD + c8 * 8];
    __half2* hv = (__half2*)&v;
    #pragma unroll
    for (int q = 0; q < 4; q++) As2[(4 * c8 + q) * 128 + row] = hv[q];
  }
  __syncthreads();

  float acc[8][8];
  #pragma unroll
  for (int i = 0; i < 8; i++)
    #pragma unroll
    for (int j = 0; j < 8; j++) acc[i][j] = 0.f;

  #pragma unroll 4
  for (int k2 = 0; k2 < 64; k2++){
    float4 ar0 = *(const float4*)&As2[k2 * 128 + ty * 8];        // m = ty*8..+3
    float4 ar1 = *(const float4*)&As2[k2 * 128 + ty * 8 + 4];    // m = +4..+7
    float4 wr0 = *(const float4*)&Wh2[k2 * 128 + tx * 4];        // n = tx*4..+3
    float4 wr1 = *(const float4*)&Wh2[k2 * 128 + 64 + tx * 4];   // n = 64+tx*4..+3
    const h2_t* av0 = (const h2_t*)&ar0;
    const h2_t* av1 = (const h2_t*)&ar1;
    const h2_t* wv0 = (const h2_t*)&wr0;
    const h2_t* wv1 = (const h2_t*)&wr1;
    #pragma unroll
    for (int i = 0; i < 8; i++){
      h2_t ai = (i < 4) ? av0[i] : av1[i - 4];
      #pragma unroll
      for (int j = 0; j < 4; j++){
        acc[i][j]     = fdot2f(ai, wv0[j], acc[i][j]);
        acc[i][j + 4] = fdot2f(ai, wv1[j], acc[i][j + 4]);
      }
    }
  }

  // store hp (fp16): two 8B chunks per row (cols tx*4 and 64+tx*4)
  #pragma unroll
  for (int i = 0; i < 8; i++){
    int r = rb + ty * 8 + i;
    if (r < N_NODES){
      float2 s0, s1;
      ((__half2*)&s0)[0] = __floats2half2_rn(acc[i][0], acc[i][1]);
      ((__half2*)&s0)[1] = __floats2half2_rn(acc[i][2], acc[i][3]);
      ((__half2*)&s1)[0] = __floats2half2_rn(acc[i][4], acc[i][5]);
      ((__half2*)&s1)[1] = __floats2half2_rn(acc[i][6], acc[i][7]);
      *(float2*)&hp_h[(size_t)r * HD + tx * 4]      = s0;
      *(float2*)&hp_h[(size_t)r * HD + 64 + tx * 4] = s1;
    }
  }

  // fused score: per-row dot with att_src/att_dst, reduce over the 16 col-groups
  float as_v[8], ad_v[8];
  #pragma unroll
  for (int j = 0; j < 4; j++){
    as_v[j]     = as_[tx * 4 + j];      ad_v[j]     = ad_[tx * 4 + j];
    as_v[j + 4] = as_[64 + tx * 4 + j]; ad_v[j + 4] = ad_[64 + tx * 4 + j];
  }
  #pragma unroll
  for (int i = 0; i < 8; i++){
    float ps = 0.f, pd = 0.f;
    #pragma unroll
    for (int j = 0; j < 8; j++){
      ps = fmaf(acc[i][j], as_v[j], ps);
      pd = fmaf(acc[i][j], ad_v[j], pd);
    }
    #pragma unroll
    for (int off = 8; off > 0; off >>= 1){
      ps += __shfl_down(ps, off, 16);
      pd += __shfl_down(pd, off, 16);
    }
    int r = rb + ty * 8 + i;
    if (tx == 0 && r < N_NODES){ ssrc[r] = ps; sdst[r] = pd; }
  }
}

// wave-cooperative attention: 16 lanes per dst node (16 nodes per 256-block).
// Lanes stride the node's CSR segment -> csr reads and wp writes are contiguous
// 128B bursts (vs 1-thread-per-node strided walk), exp runs 16-wide, and the
// denominator is a width-16 shfl_xor reduce. No atomics.
__global__ __launch_bounds__(256) void attn_kernel(const int* __restrict__ rowstart,
                                                   const int2* __restrict__ csr,
                                                   const float* __restrict__ eattr,
                                                   const float* __restrict__ ssrc,
                                                   const float* __restrict__ sdst,
                                                   const float* __restrict__ scal, int which,
                                                   float* __restrict__ wp,
                                                   float* __restrict__ pinv){
  int sub  = threadIdx.x >> 4;     // 0..15 node slot
  int lane = threadIdx.x & 15;
  int n = blockIdx.x * 16 + sub;
  if (n >= N_NODES) return;
  int s0 = rowstart[n];
  int s1 = (n + 1 < N_NODES) ? rowstart[n + 1] : TOT;
  float sd = sdst[n];
  float ce = scal[1 + which];
  float mean_ea = scal[0] * (1.0f / (float)N_EDGES);
  float sum = 0.f;
  for (int i = s0 + lane; i < s1; i += 16){
    int2 se = csr[i];
    float eav = (se.y < N_EDGES) ? eattr[se.y] : mean_ea;
    float a = ssrc[se.x] + sd + eav * ce;
    a = (a >= 0.f) ? a : NEG_SLOPE * a;   // leaky_relu
    float w = expf(a);
    wp[i] = w;
    sum += w;
  }
  #pragma unroll
  for (int off = 8; off > 0; off >>= 1) sum += __shfl_xor(sum, off, 16);
  if (lane == 0) pinv[n] = 1.0f / (sum + 1e-16f);
}

// aggregation: 16 lanes per dst node (4 nodes per wave, 16 per 256-block),
// lane covers 8 cols (float4 = 16B of fp16) -> half the VMEM instructions of
// the 32-lane/float2 version, 2x nodes in flight per wave. Edge loop unrolled
// x4; weights/csr read broadcast; 1/denom folded into the epilogue.
__global__ __launch_bounds__(256) void agg_kernel(const int* __restrict__ rowstart,
                                                  const int2* __restrict__ csr,
                                                  const float* __restrict__ wp,
                                                  const float* __restrict__ pinv,
                                                  const __half* __restrict__ hp_h,
                                                  const float* __restrict__ bias,
                                                  __half* __restrict__ hnext,
                                                  float* __restrict__ out, int outoff){
  int sub  = threadIdx.x >> 4;     // 0..15 node slot
  int lane = threadIdx.x & 15;     // covers cols 8*lane .. +7
  int n = blockIdx.x * 16 + sub;
  if (n >= N_NODES) return;
  int s0 = rowstart[n];
  int s1 = (n + 1 < N_NODES) ? rowstart[n + 1] : TOT;
  const float4* hb = (const float4*)hp_h;   // one float4 = 8 halves; row stride = 16

  float a0 = 0.f, a1 = 0.f, a2 = 0.f, a3 = 0.f;
  float a4 = 0.f, a5 = 0.f, a6 = 0.f, a7 = 0.f;

#define ACC8(r, p) { const __half2* hh = (const __half2*)&(r); float2 f;         \
    f = __half22float2(hh[0]); a0 = fmaf(p, f.x, a0); a1 = fmaf(p, f.y, a1);     \
    f = __half22float2(hh[1]); a2 = fmaf(p, f.x, a2); a3 = fmaf(p, f.y, a3);     \
    f = __half22float2(hh[2]); a4 = fmaf(p, f.x, a4); a5 = fmaf(p, f.y, a5);     \
    f = __half22float2(hh[3]); a6 = fmaf(p, f.x, a6); a7 = fmaf(p, f.y, a7); }

  int i = s0;
  for (; i + 4 <= s1; i += 4){
    int2 se0 = csr[i],     se1 = csr[i + 1];
    int2 se2 = csr[i + 2], se3 = csr[i + 3];
    float p0 = wp[i],     p1 = wp[i + 1];
    float p2 = wp[i + 2], p3 = wp[i + 3];
    float4 r0 = hb[(size_t)se0.x * 16 + lane];
    float4 r1 = hb[(size_t)se1.x * 16 + lane];
    float4 r2 = hb[(size_t)se2.x * 16 + lane];
    float4 r3 = hb[(size_t)se3.x * 16 + lane];
    ACC8(r0, p0); ACC8(r1, p1); ACC8(r2, p2); ACC8(r3, p3);
  }
  for (; i < s1; i++){
    int2 se = csr[i];
    float p = wp[i];
    float4 r = hb[(size_t)se.x * 16 + lane];
    ACC8(r, p);
  }
#undef ACC8

  float inv = pinv[n];
  float4 bA = *(const float4*)&bias[lane * 8];
  float4 bB = *(const float4*)&bias[lane * 8 + 4];
  float v0 = fmaf(a0, inv, bA.x); v0 = v0 > 0.f ? v0 : 0.f;
  float v1 = fmaf(a1, inv, bA.y); v1 = v1 > 0.f ? v1 : 0.f;
  float v2 = fmaf(a2, inv, bA.z); v2 = v2 > 0.f ? v2 : 0.f;
  float v3 = fmaf(a3, inv, bA.w); v3 = v3 > 0.f ? v3 : 0.f;
  float v4 = fmaf(a4, inv, bB.x); v4 = v4 > 0.f ? v4 : 0.f;
  float v5 = fmaf(a5, inv, bB.y); v5 = v5 > 0.f ? v5 : 0.f;
  float v6 = fmaf(a6, inv, bB.z); v6 = v6 > 0.f ? v6 : 0.f;
  float v7 = fmaf(a7, inv, bB.w); v7 = v7 > 0.f ? v7 : 0.f;
  if (hnext){
    float4 pk;
    __half2* p2h = (__half2*)&pk;
    p2h[0] = __floats2half2_rn(v0, v1);
    p2h[1] = __floats2half2_rn(v2, v3);
    p2h[2] = __floats2half2_rn(v4, v5);
    p2h[3] = __floats2half2_rn(v6, v7);
    *(float4*)&hnext[(size_t)n * HD + lane * 8] = pk;
  }
  *(float4*)&out[(size_t)n * OUTW + outoff + lane * 8]     = make_float4(v0, v1, v2, v3);
  *(float4*)&out[(size_t)n * OUTW + outoff + lane * 8 + 4] = make_float4(v4, v5, v6, v7);
}

// ---------- launch ----------

extern "C" void kernel_launch(void* const* d_in, const int* in_sizes, int n_in,
                              void* d_out, int out_size, void* d_ws, size_t ws_size,
                              hipStream_t stream){
  (void)in_sizes; (void)n_in; (void)out_size; (void)ws_size;
  const float* x    = (const float*)d_in[0];
  const void*  ei   = d_in[1];
  const float* eatt = (const float*)d_in[2];
  const float* W0   = (const float*)d_in[3];
  const float* as0  = (const float*)d_in[4];
  const float* ad0  = (const float*)d_in[5];
  const float* We0  = (const float*)d_in[6];
  const float* ae0  = (const float*)d_in[7];
  const float* b0   = (const float*)d_in[8];
  const float* W1   = (const float*)d_in[9];
  const float* as1  = (const float*)d_in[10];
  const float* ad1  = (const float*)d_in[11];
  const float* We1  = (const float*)d_in[12];
  const float* ae1  = (const float*)d_in[13];
  const float* b1   = (const float*)d_in[14];
  float* out = (float*)d_out;

  char* ws = (char*)d_ws;
  size_t off = 0;
  auto alloc = [&](size_t bytes) -> void* {
    void* p = ws + off;
    off += (bytes + 255) & ~(size_t)255;
    return p;
  };
  __half*   hp_h     = (__half*)  alloc((size_t)N_NODES * HD * 2);
  __half*   h1       = (__half*)  alloc((size_t)N_NODES * HD * 2);
  __half*   x16      = (__half*)  alloc((size_t)N_NODES * HD * 2);
  float*    ssrc     = (float*)   alloc((size_t)N_NODES * 4);
  float*    sdst     = (float*)   alloc((size_t)N_NODES * 4);
  float*    wp       = (float*)   alloc((size_t)TOT * 4);
  float*    pinv     = (float*)   alloc((size_t)N_NODES * 4);
  int*      deg      = (int*)     alloc((size_t)N_NODES * 4);
  int*      rowstart = (int*)     alloc((size_t)N_NODES * 4);
  int*      rowcur   = (int*)     alloc((size_t)N_NODES * 4);
  int*      src32    = (int*)     alloc((size_t)N_EDGES * 4);
  int*      dst32    = (int*)     alloc((size_t)N_EDGES * 4);
  int2*     csr      = (int2*)    alloc((size_t)TOT * 8);
  __half2*  Wt0      = (__half2*) alloc((size_t)8192 * 4);
  __half2*  Wt1      = (__half2*) alloc((size_t)8192 * 4);
  int*      chunksums= (int*)     alloc(64 * 4);
  float*    scal     = (float*)   alloc(64 * 4);   // [0]=sum(edge_attr) [1]=ce0 [2]=ce1
  int*      flag     = (int*)     alloc(64);

  hipMemsetAsync(deg, 0, (size_t)N_NODES * 4, stream);

  const int EB = (TOT + 255) / 256;
  const int nchunks = (N_NODES + 1023) / 1024;

  prep_kernel<<<1, 128, 0, stream>>>(ei, flag, We0, ae0, We1, ae1, scal);
  wconv_kernel<<<64, 256, 0, stream>>>(W0, W1, Wt0, Wt1);
  xconv_kernel<<<(N_NODES * HD / 4 + 255) / 256, 256, 0, stream>>>(x, x16, out);
  mean_kernel<<<256, 256, 0, stream>>>(eatt, scal);
  degconv_kernel<<<EB, 256, 0, stream>>>(ei, flag, deg, src32, dst32);
  scan_chunk_kernel<<<nchunks, 256, 0, stream>>>(deg, rowstart, chunksums);
  scan_top_kernel<<<1, 64, 0, stream>>>(chunksums, nchunks);
  add_off_kernel<<<nchunks, 256, 0, stream>>>(rowstart, rowcur, chunksums);
  fill_kernel<<<EB, 256, 0, stream>>>(src32, dst32, rowcur, csr);

  const int GB = (N_NODES + BM - 1) / BM;   // 391
  const int NB16 = (N_NODES + 15) / 16;     // 3125: attn + agg blocks (16 nodes/block)

  // layer 0
  gemm_kernel<<<GB, 256, 0, stream>>>(x16, Wt0, hp_h, as0, ad0, ssrc, sdst);
  attn_kernel<<<NB16, 256, 0, stream>>>(rowstart, csr, eatt, ssrc, sdst, scal, 0, wp, pinv);
  agg_kernel<<<NB16, 256, 0, stream>>>(rowstart, csr, wp, pinv, hp_h, b0, h1, out, 128);

  // layer 1
  gemm_kernel<<<GB, 256, 0, stream>>>(h1, Wt1, hp_h, as1, ad1, ssrc, sdst);
  attn_kernel<<<NB16, 256, 0, stream>>>(rowstart, csr, eatt, ssrc, sdst, scal, 1, wp, pinv);
  agg_kernel<<<NB16, 256, 0, stream>>>(rowstart, csr, wp, pinv, hp_h, b1, nullptr, out, 256);
}

// Round 2
// 324.628 us; speedup vs baseline: 1.0493x; 1.0493x over previous
//
#include <hip/hip_runtime.h>
#include <hip/hip_fp16.h>
#include <math.h>

#define N_NODES 50000
#define N_EDGES 600000
#define TOT (N_EDGES + N_NODES)   // 650000 edges incl. self-loops
#define HD 128
#define OUTW 384
#define NEG_SLOPE 0.2f

// ---------- helpers ----------

typedef _Float16 h2_t __attribute__((ext_vector_type(2)));

static __device__ __forceinline__ float fdot2f(h2_t a, h2_t b, float c){
#if __has_builtin(__builtin_amdgcn_fdot2)
  return __builtin_amdgcn_fdot2(a, b, c, false);
#else
  return fmaf((float)a[0], (float)b[0], fmaf((float)a[1], (float)b[1], c));
#endif
}

// edge_index may arrive as int32 or int64; runtime-detected flag (uniform branch)
static __device__ __forceinline__ int load_edge(const void* ei, int is64, long long off){
  return is64 ? (int)((const long long*)ei)[off] : ((const int*)ei)[off];
}

// ---------- one-time per-launch kernels ----------

// fused: int64-layout detect + ce0/ce1 = dot(We, att_e) (block 0 only)
//      + grid-wide partial sums of edge_attr into scal[0] (pre-zeroed by memset)
__global__ __launch_bounds__(256) void prep_kernel(const void* ei, int* flag,
                                                   const float* __restrict__ We0, const float* __restrict__ ae0,
                                                   const float* __restrict__ We1, const float* __restrict__ ae1,
                                                   float* scal, const float* __restrict__ eattr){
  int t = threadIdx.x;
  if (blockIdx.x == 0){
    __shared__ float buf[128];
    __shared__ int okbuf;
    if (t == 0) okbuf = 1;
    __syncthreads();
    if (t < 64){
      long long v = ((const long long*)ei)[t];
      if (v < 0 || v >= N_NODES) atomicAnd(&okbuf, 0);
    }
    if (t < 128) buf[t] = We0[t] * ae0[t];
    __syncthreads();
    for (int off = 64; off > 0; off >>= 1){ if (t < off) buf[t] += buf[t + off]; __syncthreads(); }
    if (t == 0) scal[1] = buf[0];
    __syncthreads();
    if (t < 128) buf[t] = We1[t] * ae1[t];
    __syncthreads();
    for (int off = 64; off > 0; off >>= 1){ if (t < off) buf[t] += buf[t + off]; __syncthreads(); }
    if (t == 0){ scal[2] = buf[0]; *flag = okbuf; }
  }
  // all 256 blocks: edge_attr mean partial sums (scal[0] zeroed by the memset)
  int tid = blockIdx.x * 256 + t;
  float s = 0.f;
  for (int i = tid; i < N_EDGES; i += 256 * 256) s += eattr[i];
  for (int off = 32; off > 0; off >>= 1) s += __shfl_down(s, off, 64);
  __shared__ float ws[4];
  int lane = t & 63, w = t >> 6;
  if (lane == 0) ws[w] = s;
  __syncthreads();
  if (t == 0) atomicAdd(&scal[0], ws[0] + ws[1] + ws[2] + ws[3]);
}

// fused elementwise conversions (all independent, all after prep):
//  blocks [0, 6250)          : x -> fp16 x16 + stream x into out[:,0:128]
//  blocks [6250, 6314)       : W0/W1 -> k-paired fp16 Wt0/Wt1
//  blocks [6314, 6314+2540)  : edge decode int64->int32 + degree count
#define XBLK 6250
#define WBLK 64
#define DBLK 2540
__global__ __launch_bounds__(256) void conv_kernel(const float* __restrict__ x,
                                                   __half* __restrict__ x16,
                                                   float* __restrict__ out,
                                                   const float* __restrict__ W0, const float* __restrict__ W1,
                                                   __half2* __restrict__ Wt0, __half2* __restrict__ Wt1,
                                                   const void* ei, const int* flag, int* deg,
                                                   int* __restrict__ src32, int* __restrict__ dst32){
  int b = blockIdx.x;
  if (b < XBLK){
    int idx = b * 256 + threadIdx.x;          // 6250*256 = 1,600,000 exact
    int n = idx >> 5, c4 = idx & 31;
    float4 v = ((const float4*)x)[idx];
    *(float4*)&out[(size_t)n * OUTW + c4 * 4] = v;
    float2 pk;
    ((__half2*)&pk)[0] = __floats2half2_rn(v.x, v.y);
    ((__half2*)&pk)[1] = __floats2half2_rn(v.z, v.w);
    *(float2*)&x16[(size_t)idx * 4] = pk;
  } else if (b < XBLK + WBLK){
    int e = (b - XBLK) * 256 + threadIdx.x;   // 0..16383 exact
    const float* W = (e < 8192) ? W0 : W1;
    __half2* Wt = (e < 8192) ? Wt0 : Wt1;
    int i = e & 8191;
    int n = i & 127, k2 = i >> 7;
    float a = W[n * HD + 2 * k2];
    float c = W[n * HD + 2 * k2 + 1];
    Wt[k2 * 128 + n] = __floats2half2_rn(a, c);
  } else {
    int e = (b - XBLK - WBLK) * 256 + threadIdx.x;
    if (e >= TOT) return;
    int is64 = *flag;
    int d;
    if (e < N_EDGES){
      int s = load_edge(ei, is64, e);
      d = load_edge(ei, is64, (long long)N_EDGES + e);
      src32[e] = s;
      dst32[e] = d;
    } else {
      d = e - N_EDGES;
    }
    atomicAdd(&deg[d], 1);
  }
}

// exclusive scan of deg[0..N) -> rowstart, 1024-element chunks
__global__ __launch_bounds__(256) void scan_chunk_kernel(const int* __restrict__ deg,
                                                         int* __restrict__ rowstart,
                                                         int* __restrict__ chunksums){
  __shared__ int sums[256];
  int t = threadIdx.x;
  int base = blockIdx.x * 1024 + t * 4;
  int v[4];
  #pragma unroll
  for (int i = 0; i < 4; i++) v[i] = (base + i < N_NODES) ? deg[base + i] : 0;
  int tsum = v[0] + v[1] + v[2] + v[3];
  sums[t] = tsum;
  __syncthreads();
  for (int off = 1; off < 256; off <<= 1){
    int add = (t >= off) ? sums[t - off] : 0;
    __syncthreads();
    sums[t] += add;
    __syncthreads();
  }
  int run = sums[t] - tsum;
  #pragma unroll
  for (int i = 0; i < 4; i++){
    if (base + i < N_NODES) rowstart[base + i] = run;
    run += v[i];
  }
  if (t == 255) chunksums[blockIdx.x] = sums[255];
}

// add chunk offsets; each block reduces its own prefix over chunksums (<=49 values,
// one 64-lane wave) -- no serial scan_top kernel. Also emits rowcur (fill cursor).
__global__ __launch_bounds__(256) void add_off_kernel(int* rowstart, int* rowcur,
                                                      const int* __restrict__ chunksums){
  __shared__ int soff;
  int t = threadIdx.x;
  if (t < 64){
    int v = (t < blockIdx.x) ? chunksums[t] : 0;
    for (int o = 32; o > 0; o >>= 1) v += __shfl_down(v, o, 64);
    if (t == 0) soff = v;
  }
  __syncthreads();
  int off = soff;
  int base = blockIdx.x * 1024 + t * 4;
  #pragma unroll
  for (int i = 0; i < 4; i++){
    if (base + i < N_NODES){
      int v = rowstart[base + i] + off;
      rowstart[base + i] = v;
      rowcur[base + i] = v;
    }
  }
}

// bucket fill: one packed int2 (src, eid) scattered store per edge
__global__ __launch_bounds__(256) void fill_kernel(const int* __restrict__ src32,
                                                   const int* __restrict__ dst32,
                                                   int* rowcur, int2* __restrict__ csr){
  int e = blockIdx.x * 256 + threadIdx.x;
  if (e >= TOT) return;
  int s, d;
  if (e < N_EDGES){
    s = src32[e];
    d = dst32[e];
  } else {
    s = d = e - N_EDGES;
  }
  int pos = atomicAdd(&rowcur[d], 1);
  csr[pos] = make_int2(s, e);
}

// ---------- per-layer kernels ----------

// fdot2 GEMM: hp_h[M,128] = fp16( hin[M,128] @ W^T ), fp16 input, W pre-packed fp16 [k2][n].
// BM=128 rows/block, 256 threads (4 waves), 8 rows x 8 cols per thread.
// LDS exactly 64 KB: A [k2][m] 32 KB + W [k2][n] 32 KB; ONE barrier; 2 blocks/CU (8 waves).
// Fused epilogue: ssrc/sdst row dots.
#define BM 128

__global__ __launch_bounds__(256, 2) void gemm_kernel(const __half* __restrict__ hin,
                                                      const __half2* __restrict__ Wt,
                                                      __half* __restrict__ hp_h,
                                                      const float* __restrict__ as_,
                                                      const float* __restrict__ ad_,
                                                      float* __restrict__ ssrc,
                                                      float* __restrict__ sdst){
  __shared__ __half2 As2[64 * 128];    // [k2][m] 32768 B
  __shared__ __half2 Wh2[64 * 128];    // [k2][n] 32768 B
  int t  = threadIdx.x;
  int tx = t & 15;
  int ty = t >> 4;                     // 0..15 -> rows ty*8..+7
  int rb = blockIdx.x * BM;

  // stage W: straight 32KB copy (coalesced, conflict-free)
  {
    const float4* src = (const float4*)Wt;
    float4* dst = (float4*)Wh2;
    #pragma unroll
    for (int p = 0; p < 8; p++) dst[t + p * 256] = src[t + p * 256];
  }
  // stage A: 128 rows x 128 halves, packed to [k2][m]
  #pragma unroll
  for (int p = 0; p < 8; p++){
    int idx = t + p * 256;             // 0..2047 float4s (8 halves each)
    int row = idx >> 4, c8 = idx & 15;
    int gr = rb + row; if (gr >= N_NODES) gr = N_NODES - 1;
    float4 v = *(const float4*)&hin[(size_t)gr * HD + c8 * 8];
    __half2* hv = (__half2*)&v;
    #pragma unroll
    for (int q = 0; q < 4; q++) As2[(4 * c8 + q) * 128 + row] = hv[q];
  }
  __syncthreads();

  float acc[8][8];
  #pragma unroll
  for (int i = 0; i < 8; i++)
    #pragma unroll
    for (int j = 0; j < 8; j++) acc[i][j] = 0.f;

  #pragma unroll 4
  for (int k2 = 0; k2 < 64; k2++){
    float4 ar0 = *(const float4*)&As2[k2 * 128 + ty * 8];        // m = ty*8..+3
    float4 ar1 = *(const float4*)&As2[k2 * 128 + ty * 8 + 4];    // m = +4..+7
    float4 wr0 = *(const float4*)&Wh2[k2 * 128 + tx * 4];        // n = tx*4..+3
    float4 wr1 = *(const float4*)&Wh2[k2 * 128 + 64 + tx * 4];   // n = 64+tx*4..+3
    const h2_t* av0 = (const h2_t*)&ar0;
    const h2_t* av1 = (const h2_t*)&ar1;
    const h2_t* wv0 = (const h2_t*)&wr0;
    const h2_t* wv1 = (const h2_t*)&wr1;
    #pragma unroll
    for (int i = 0; i < 8; i++){
      h2_t ai = (i < 4) ? av0[i] : av1[i - 4];
      #pragma unroll
      for (int j = 0; j < 4; j++){
        acc[i][j]     = fdot2f(ai, wv0[j], acc[i][j]);
        acc[i][j + 4] = fdot2f(ai, wv1[j], acc[i][j + 4]);
      }
    }
  }

  // store hp (fp16): two 8B chunks per row (cols tx*4 and 64+tx*4)
  #pragma unroll
  for (int i = 0; i < 8; i++){
    int r = rb + ty * 8 + i;
    if (r < N_NODES){
      float2 s0, s1;
      ((__half2*)&s0)[0] = __floats2half2_rn(acc[i][0], acc[i][1]);
      ((__half2*)&s0)[1] = __floats2half2_rn(acc[i][2], acc[i][3]);
      ((__half2*)&s1)[0] = __floats2half2_rn(acc[i][4], acc[i][5]);
      ((__half2*)&s1)[1] = __floats2half2_rn(acc[i][6], acc[i][7]);
      *(float2*)&hp_h[(size_t)r * HD + tx * 4]      = s0;
      *(float2*)&hp_h[(size_t)r * HD + 64 + tx * 4] = s1;
    }
  }

  // fused score: per-row dot with att_src/att_dst, reduce over the 16 col-groups
  float as_v[8], ad_v[8];
  #pragma unroll
  for (int j = 0; j < 4; j++){
    as_v[j]     = as_[tx * 4 + j];      ad_v[j]     = ad_[tx * 4 + j];
    as_v[j + 4] = as_[64 + tx * 4 + j]; ad_v[j + 4] = ad_[64 + tx * 4 + j];
  }
  #pragma unroll
  for (int i = 0; i < 8; i++){
    float ps = 0.f, pd = 0.f;
    #pragma unroll
    for (int j = 0; j < 8; j++){
      ps = fmaf(acc[i][j], as_v[j], ps);
      pd = fmaf(acc[i][j], ad_v[j], pd);
    }
    #pragma unroll
    for (int off = 8; off > 0; off >>= 1){
      ps += __shfl_down(ps, off, 16);
      pd += __shfl_down(pd, off, 16);
    }
    int r = rb + ty * 8 + i;
    if (tx == 0 && r < N_NODES){ ssrc[r] = ps; sdst[r] = pd; }
  }
}

// fused attention + aggregation: 16 lanes per dst node (16 nodes per 256-block).
// Each group computes the exp-weights INLINE (ssrc/eattr loads are same-address
// broadcasts across the 16 lanes; exp is redundant x16 but ~free on the VALU),
// accumulating both the softmax denominator and the weighted feature sum in one
// pass. Eliminates the attn kernel and all wp/pinv global traffic.
__global__ __launch_bounds__(256) void agg_kernel(const int* __restrict__ rowstart,
                                                  const int2* __restrict__ csr,
                                                  const float* __restrict__ eattr,
                                                  const float* __restrict__ ssrc,
                                                  const float* __restrict__ sdst,
                                                  const float* __restrict__ scal, int which,
                                                  const __half* __restrict__ hp_h,
                                                  const float* __restrict__ bias,
                                                  __half* __restrict__ hnext,
                                                  float* __restrict__ out, int outoff){
  int sub  = threadIdx.x >> 4;     // 0..15 node slot
  int lane = threadIdx.x & 15;     // covers cols 8*lane .. +7
  int n = blockIdx.x * 16 + sub;
  if (n >= N_NODES) return;
  int s0 = rowstart[n];
  int s1 = (n + 1 < N_NODES) ? rowstart[n + 1] : TOT;
  float sd = sdst[n];
  float ce = scal[1 + which];
  float mean_ea = scal[0] * (1.0f / (float)N_EDGES);
  const float4* hb = (const float4*)hp_h;   // one float4 = 8 halves; row stride = 16

  float a0 = 0.f, a1 = 0.f, a2 = 0.f, a3 = 0.f;
  float a4 = 0.f, a5 = 0.f, a6 = 0.f, a7 = 0.f;
  float sum = 0.f;

#define EW(se) ({ float eav = ((se).y < N_EDGES) ? eattr[(se).y] : mean_ea;       \
    float al = ssrc[(se).x] + sd + eav * ce;                                      \
    al = (al >= 0.f) ? al : NEG_SLOPE * al;                                       \
    expf(al); })

#define ACC8(r, p) { const __half2* hh = (const __half2*)&(r); float2 f;         \
    f = __half22float2(hh[0]); a0 = fmaf(p, f.x, a0); a1 = fmaf(p, f.y, a1);     \
    f = __half22float2(hh[1]); a2 = fmaf(p, f.x, a2); a3 = fmaf(p, f.y, a3);     \
    f = __half22float2(hh[2]); a4 = fmaf(p, f.x, a4); a5 = fmaf(p, f.y, a5);     \
    f = __half22float2(hh[3]); a6 = fmaf(p, f.x, a6); a7 = fmaf(p, f.y, a7); }

  int i = s0;
  for (; i + 4 <= s1; i += 4){
    int2 se0 = csr[i],     se1 = csr[i + 1];
    int2 se2 = csr[i + 2], se3 = csr[i + 3];
    float4 r0 = hb[(size_t)se0.x * 16 + lane];
    float4 r1 = hb[(size_t)se1.x * 16 + lane];
    float4 r2 = hb[(size_t)se2.x * 16 + lane];
    float4 r3 = hb[(size_t)se3.x * 16 + lane];
    float p0 = EW(se0), p1 = EW(se1), p2 = EW(se2), p3 = EW(se3);
    sum += p0 + p1 + p2 + p3;
    ACC8(r0, p0); ACC8(r1, p1); ACC8(r2, p2); ACC8(r3, p3);
  }
  for (; i < s1; i++){
    int2 se = csr[i];
    float4 r = hb[(size_t)se.x * 16 + lane];
    float p = EW(se);
    sum += p;
    ACC8(r, p);
  }
#undef ACC8
#undef EW

  float inv = 1.0f / (sum + 1e-16f);
  float4 bA = *(const float4*)&bias[lane * 8];
  float4 bB = *(const float4*)&bias[lane * 8 + 4];
  float v0 = fmaf(a0, inv, bA.x); v0 = v0 > 0.f ? v0 : 0.f;
  float v1 = fmaf(a1, inv, bA.y); v1 = v1 > 0.f ? v1 : 0.f;
  float v2 = fmaf(a2, inv, bA.z); v2 = v2 > 0.f ? v2 : 0.f;
  float v3 = fmaf(a3, inv, bA.w); v3 = v3 > 0.f ? v3 : 0.f;
  float v4 = fmaf(a4, inv, bB.x); v4 = v4 > 0.f ? v4 : 0.f;
  float v5 = fmaf(a5, inv, bB.y); v5 = v5 > 0.f ? v5 : 0.f;
  float v6 = fmaf(a6, inv, bB.z); v6 = v6 > 0.f ? v6 : 0.f;
  float v7 = fmaf(a7, inv, bB.w); v7 = v7 > 0.f ? v7 : 0.f;
  if (hnext){
    float4 pk;
    __half2* p2h = (__half2*)&pk;
    p2h[0] = __floats2half2_rn(v0, v1);
    p2h[1] = __floats2half2_rn(v2, v3);
    p2h[2] = __floats2half2_rn(v4, v5);
    p2h[3] = __floats2half2_rn(v6, v7);
    *(float4*)&hnext[(size_t)n * HD + lane * 8] = pk;
  }
  *(float4*)&out[(size_t)n * OUTW + outoff + lane * 8]     = make_float4(v0, v1, v2, v3);
  *(float4*)&out[(size_t)n * OUTW + outoff + lane * 8 + 4] = make_float4(v4, v5, v6, v7);
}

// ---------- launch ----------

extern "C" void kernel_launch(void* const* d_in, const int* in_sizes, int n_in,
                              void* d_out, int out_size, void* d_ws, size_t ws_size,
                              hipStream_t stream){
  (void)in_sizes; (void)n_in; (void)out_size; (void)ws_size;
  const float* x    = (const float*)d_in[0];
  const void*  ei   = d_in[1];
  const float* eatt = (const float*)d_in[2];
  const float* W0   = (const float*)d_in[3];
  const float* as0  = (const float*)d_in[4];
  const float* ad0  = (const float*)d_in[5];
  const float* We0  = (const float*)d_in[6];
  const float* ae0  = (const float*)d_in[7];
  const float* b0   = (const float*)d_in[8];
  const float* W1   = (const float*)d_in[9];
  const float* as1  = (const float*)d_in[10];
  const float* ad1  = (const float*)d_in[11];
  const float* We1  = (const float*)d_in[12];
  const float* ae1  = (const float*)d_in[13];
  const float* b1   = (const float*)d_in[14];
  float* out = (float*)d_out;

  char* ws = (char*)d_ws;
  size_t off = 0;
  auto alloc = [&](size_t bytes) -> void* {
    void* p = ws + off;
    off += (bytes + 255) & ~(size_t)255;
    return p;
  };
  __half*   hp_h     = (__half*)  alloc((size_t)N_NODES * HD * 2);
  __half*   h1       = (__half*)  alloc((size_t)N_NODES * HD * 2);
  __half*   x16      = (__half*)  alloc((size_t)N_NODES * HD * 2);
  float*    ssrc     = (float*)   alloc((size_t)N_NODES * 4);
  float*    sdst     = (float*)   alloc((size_t)N_NODES * 4);
  // deg and scal MUST stay adjacent: one memset zeroes both (scal[0] is the
  // atomicAdd target for the edge_attr sum; deg is the degree counter array)
  int*      deg      = (int*)     alloc((size_t)N_NODES * 4);   // 200000 -> padded 200192
  float*    scal     = (float*)   alloc(64 * 4);                // [0]=sum(ea) [1]=ce0 [2]=ce1
  int*      rowstart = (int*)     alloc((size_t)N_NODES * 4);
  int*      rowcur   = (int*)     alloc((size_t)N_NODES * 4);
  int*      src32    = (int*)     alloc((size_t)N_EDGES * 4);
  int*      dst32    = (int*)     alloc((size_t)N_EDGES * 4);
  int2*     csr      = (int2*)    alloc((size_t)TOT * 8);
  __half2*  Wt0      = (__half2*) alloc((size_t)8192 * 4);
  __half2*  Wt1      = (__half2*) alloc((size_t)8192 * 4);
  int*      chunksums= (int*)     alloc(64 * 4);
  int*      flag     = (int*)     alloc(64);

  // zero deg (200192 B incl. padding) + scal (256 B) in one shot
  hipMemsetAsync(deg, 0, 200192 + 256, stream);

  const int nchunks = (N_NODES + 1023) / 1024;   // 49
  const int FB = (TOT + 255) / 256;              // 2540

  prep_kernel<<<256, 256, 0, stream>>>(ei, flag, We0, ae0, We1, ae1, scal, eatt);
  conv_kernel<<<XBLK + WBLK + DBLK, 256, 0, stream>>>(x, x16, out, W0, W1, Wt0, Wt1,
                                                      ei, flag, deg, src32, dst32);
  scan_chunk_kernel<<<nchunks, 256, 0, stream>>>(deg, rowstart, chunksums);
  add_off_kernel<<<nchunks, 256, 0, stream>>>(rowstart, rowcur, chunksums);
  fill_kernel<<<FB, 256, 0, stream>>>(src32, dst32, rowcur, csr);

  const int GB = (N_NODES + BM - 1) / BM;   // 391
  const int NB16 = (N_NODES + 15) / 16;     // 3125

  // layer 0
  gemm_kernel<<<GB, 256, 0, stream>>>(x16, Wt0, hp_h, as0, ad0, ssrc, sdst);
  agg_kernel<<<NB16, 256, 0, stream>>>(rowstart, csr, eatt, ssrc, sdst, scal, 0, hp_h, b0, h1, out, 128);

  // layer 1
  gemm_kernel<<<GB, 256, 0, stream>>>(h1, Wt1, hp_h, as1, ad1, ssrc, sdst);
  agg_kernel<<<NB16, 256, 0, stream>>>(rowstart, csr, eatt, ssrc, sdst, scal, 1, hp_h, b1, nullptr, out, 256);
}